// Round 2
// baseline (1035.029 us; speedup 1.0000x reference)
//
#include <hip/hip_runtime.h>

typedef float f32x4 __attribute__((ext_vector_type(4)));
typedef short s16x8 __attribute__((ext_vector_type(8)));
typedef unsigned int u32;

#define BSZ 4
#define SEQ 4096
#define DIM 256
#define NH 10
#define NG 4
#define CHK 1024
#define BS_TOT 16384   // BSZ*SEQ
#define HD 2560        // NH*DIM

__device__ __forceinline__ unsigned short f2bf(float f) {
    unsigned int u = __builtin_bit_cast(unsigned int, f);
    u = (u + 0x7fffu + ((u >> 16) & 1u)) >> 16;
    return (unsigned short)u;
}

__device__ __forceinline__ void gload_lds16(const unsigned short* g, unsigned short* l) {
    __builtin_amdgcn_global_load_lds((const __attribute__((address_space(1))) u32*)g,
                                     (__attribute__((address_space(3))) u32*)l, 16, 0, 0);
}

// ---------------- cast / transpose helpers ----------------

__global__ __launch_bounds__(256) void cast_f32_bf16(const float* __restrict__ s,
                                                     unsigned short* __restrict__ d, int n) {
    long i = 4L * (blockIdx.x * 256 + threadIdx.x);
    if (i < n) {
        float4 v = *(const float4*)(s + i);
        ushort4 o;
        o.x = f2bf(v.x); o.y = f2bf(v.y); o.z = f2bf(v.z); o.w = f2bf(v.w);
        *(ushort4*)(d + i) = o;
    }
}

// Wt[h][e][d] = W[h][d][e], fp32 -> bf16.  grid (8,8,2*NH), block 256
__global__ __launch_bounds__(256) void transpose_cast_w(const float* __restrict__ Wq,
                                                        const float* __restrict__ Wk,
                                                        unsigned short* __restrict__ wqt,
                                                        unsigned short* __restrict__ wkt) {
    const float* W = (blockIdx.z & 1) ? Wk : Wq;
    unsigned short* Wt = (blockIdx.z & 1) ? wkt : wqt;
    int h = blockIdx.z >> 1;
    __shared__ float tile[32][33];
    int d0 = blockIdx.x * 32, e0 = blockIdx.y * 32;
    int tx = threadIdx.x & 31, ty = threadIdx.x >> 5;
    const float* Wh = W + (long)h * 65536;
    unsigned short* Wth = Wt + (long)h * 65536;
#pragma unroll
    for (int r = ty; r < 32; r += 8) tile[r][tx] = Wh[(long)(d0 + r) * 256 + e0 + tx];
    __syncthreads();
#pragma unroll
    for (int r = ty; r < 32; r += 8) Wth[(long)(e0 + r) * 256 + d0 + tx] = f2bf(tile[tx][r]);
}

// ---------------- generic C[m][n] = sum_k A[m][k] * Bt[n][k], N=256 ----------------
// block 256 thr (4 waves), M-tile 64 (wave w: rows 16w..16w+15)
// Optional KTo: transposed bf16 store KTo[bg][col][key] (bg = m>>10, key = m&1023)

__device__ __forceinline__ void gemm_body(const unsigned short* __restrict__ A, long lda,
                                          const unsigned short* __restrict__ Bt, long ldb,
                                          unsigned short* Cb, float* Cf, long ldc,
                                          int K, bool accum, long mbase,
                                          unsigned short* KTo) {
    __shared__ unsigned short As[64 * 40];
    __shared__ unsigned short Bs[256 * 40];
    const int t = threadIdx.x;
    const int w = t >> 6, l = t & 63, lr = l & 15, lg = l >> 4;

    f32x4 acc[16];
#pragma unroll
    for (int i = 0; i < 16; i++) acc[i] = (f32x4){0.f, 0.f, 0.f, 0.f};

    const int ar = t >> 2, akc = (t & 3) * 8;

    for (int k0 = 0; k0 < K; k0 += 32) {
        *(s16x8*)(&As[ar * 40 + akc]) = *(const s16x8*)(A + (mbase + ar) * lda + k0 + akc);
#pragma unroll
        for (int s = 0; s < 4; s++) {
            int n = s * 64 + (t >> 2);
            *(s16x8*)(&Bs[n * 40 + akc]) = *(const s16x8*)(Bt + (long)n * ldb + k0 + akc);
        }
        __syncthreads();
        s16x8 af = *(const s16x8*)(&As[(w * 16 + lr) * 40 + lg * 8]);
        __builtin_amdgcn_s_setprio(1);
#pragma unroll
        for (int nt = 0; nt < 16; nt++) {
            s16x8 bf = *(const s16x8*)(&Bs[(nt * 16 + lr) * 40 + lg * 8]);
            acc[nt] = __builtin_amdgcn_mfma_f32_16x16x32_bf16(af, bf, acc[nt], 0, 0, 0);
        }
        __builtin_amdgcn_s_setprio(0);
        __syncthreads();
    }
    long m0 = mbase + w * 16 + lg * 4;
#pragma unroll
    for (int nt = 0; nt < 16; nt++) {
        int col = nt * 16 + lr;
#pragma unroll
        for (int r = 0; r < 4; r++) {
            long idx = (m0 + r) * ldc + col;
            if (Cb) {
                Cb[idx] = f2bf(acc[nt][r]);
            } else {
                float v = acc[nt][r];
                if (accum) v += Cf[idx];
                Cf[idx] = v;
            }
        }
    }
    if (KTo) {
        int bg = (int)(m0 >> 10);
        int key0 = (int)(m0 & 1023);
        unsigned short* base = KTo + ((long)bg * 256) * 1024 + key0;
#pragma unroll
        for (int nt = 0; nt < 16; nt++) {
            int col = nt * 16 + lr;
            ushort4 v;
            v.x = f2bf(acc[nt][0]); v.y = f2bf(acc[nt][1]);
            v.z = f2bf(acc[nt][2]); v.w = f2bf(acc[nt][3]);
            *(ushort4*)(base + (long)col * 1024) = v;
        }
    }
}

// grid (256, nh, 2)
__global__ __launch_bounds__(256) void proj_kernel(const unsigned short* __restrict__ xb,
                                                   const unsigned short* __restrict__ wqt,
                                                   const unsigned short* __restrict__ wkt,
                                                   unsigned short* Qb, unsigned short* Kb,
                                                   unsigned short* KTb,
                                                   int h0, long headStrideOut, long headStrideKT) {
    int h = h0 + blockIdx.y;
    bool isK = (blockIdx.z != 0);
    const unsigned short* Bt = (isK ? wkt : wqt) + (long)h * 65536;
    unsigned short* C = (isK ? Kb : Qb) + (long)blockIdx.y * headStrideOut;
    unsigned short* KTo = isK ? (KTb + (long)blockIdx.y * headStrideKT) : nullptr;
    gemm_body(xb, 256, Bt, 256, C, nullptr, 256, 256, false, (long)blockIdx.x * 64, KTo);
}

// grid (256,1,1)
__global__ __launch_bounds__(256) void final_kernel(const unsigned short* __restrict__ Ob, long lda,
                                                    const unsigned short* __restrict__ wob, long ldb,
                                                    float* out, int K, int accum) {
    gemm_body(Ob, lda, wob, ldb, nullptr, out, 256, K, accum != 0, (long)blockIdx.x * 64, nullptr);
}

// ---------------- attention ----------------
// grid (CHK/64=16, BSZ*NG=16, nh), block 256.  wave w: q rows [64*bx + 16w, +16)
// chunk g attends KV chunk (g+1)%4.  V == K.
// Krm: [32 keys][256 d] with 16B-chunk slots XOR'd by (row&7)     (QK^T A-frags)
// KTt: [256 d][32 keys] with 16B-chunk slots XOR'd by ((d>>1)&3)  (PV B-frags)

__global__ __launch_bounds__(256) void attn_kernel(const unsigned short* __restrict__ Qb,
                                                   const unsigned short* __restrict__ Kb,
                                                   long headStrideQK,
                                                   const unsigned short* __restrict__ KTg,
                                                   long headStrideKT,
                                                   unsigned short* __restrict__ Ob,
                                                   long ldo, long colStride) {
    const int h = blockIdx.z;
    const unsigned short* Q = Qb + (long)h * headStrideQK;
    const unsigned short* Kp = Kb + (long)h * headStrideQK;
    const unsigned short* KT = KTg + (long)h * headStrideKT;
    unsigned short* O = Ob + (long)h * colStride;
    const int b = blockIdx.y >> 2, g = blockIdx.y & 3;
    const long qrow0 = (long)b * SEQ + (long)g * CHK + (long)blockIdx.x * 64;
    const long krow0 = (long)b * SEQ + (long)((g + 1) & 3) * CHK;
    const unsigned short* KTc = KT + ((long)(b * NG + ((g + 1) & 3)) * 256) * 1024;

    __shared__ unsigned short Krm[32 * 256];  // 16KB
    __shared__ unsigned short KTt[256 * 32];  // 16KB

    const int t = threadIdx.x;
    const int w = t >> 6, l = t & 63, lr = l & 15, lg = l >> 4;

    // Q fragments: lane holds Q[q=lr][d = s*32 + lg*8 + j]
    s16x8 qf[8];
    {
        const unsigned short* qp = Q + (qrow0 + w * 16 + lr) * 256 + lg * 8;
#pragma unroll
        for (int s = 0; s < 8; s++) qf[s] = *(const s16x8*)(qp + s * 32);
    }

    f32x4 o[16];
#pragma unroll
    for (int i = 0; i < 16; i++) o[i] = (f32x4){0.f, 0.f, 0.f, 0.f};
    float m_run = -1e30f, l_part = 0.f;

    // staging lane decomposition (per-wave global_load_lds, linear LDS dest)
    const int kA_row = l >> 5, kA_slot = l & 31;   // Krm: 2 rows x 32 slots per inst
    const int kT_roff = l >> 2, kT_slot = l & 3;   // KTt: 16 rows x 4 slots per inst

    for (int kt = 0; kt < 32; ++kt) {
        const unsigned short* Ksrc = Kp + (krow0 + kt * 32) * 256;
        const unsigned short* Tsrc = KTc + kt * 32;
#pragma unroll
        for (int i = 0; i < 4; i++) {
            int rb = w * 8 + i * 2;
            int row = rb + kA_row;
            int c = kA_slot ^ (row & 7);
            gload_lds16(Ksrc + row * 256 + c * 8, &Krm[rb * 256]);
        }
#pragma unroll
        for (int i = 0; i < 4; i++) {
            int rb = w * 64 + i * 16;
            int row = rb + kT_roff;
            int c = kT_slot ^ ((row >> 1) & 3);
            gload_lds16(Tsrc + (long)row * 1024 + c * 8, &KTt[rb * 32]);
        }
        __syncthreads();

        // St = K_tile @ Q^T : lane owns q=lr (col), keys lg*4 + r (st0) / 16+lg*4+r (st1)
        f32x4 st0 = (f32x4){0.f, 0.f, 0.f, 0.f}, st1 = st0;
        __builtin_amdgcn_s_setprio(1);
#pragma unroll
        for (int s = 0; s < 8; s++) {
            int c0 = ((s * 4 + lg) ^ (lr & 7)) * 8;
            s16x8 a0 = *(const s16x8*)(&Krm[lr * 256 + c0]);
            s16x8 a1 = *(const s16x8*)(&Krm[(16 + lr) * 256 + c0]);
            st0 = __builtin_amdgcn_mfma_f32_16x16x32_bf16(a0, qf[s], st0, 0, 0, 0);
            st1 = __builtin_amdgcn_mfma_f32_16x16x32_bf16(a1, qf[s], st1, 0, 0, 0);
        }
        __builtin_amdgcn_s_setprio(0);

        // online softmax for q = lr, defer-max (THR=8)
        float vmax = fmaxf(fmaxf(fmaxf(st0[0], st0[1]), fmaxf(st0[2], st0[3])),
                           fmaxf(fmaxf(st1[0], st1[1]), fmaxf(st1[2], st1[3])));
        vmax = fmaxf(vmax, __shfl_xor(vmax, 16));
        vmax = fmaxf(vmax, __shfl_xor(vmax, 32));
        if (!__all(vmax <= m_run + 8.0f)) {
            float m_new = fmaxf(m_run, vmax);
            float scale = __expf(m_run - m_new);
            m_run = m_new;
            l_part *= scale;
            float sc[4];
#pragma unroll
            for (int r = 0; r < 4; r++) sc[r] = __shfl(scale, lg * 4 + r);
#pragma unroll
            for (int nt = 0; nt < 16; nt++) {
                o[nt][0] *= sc[0]; o[nt][1] *= sc[1]; o[nt][2] *= sc[2]; o[nt][3] *= sc[3];
            }
        }
        float p[8];
#pragma unroll
        for (int i = 0; i < 4; i++) {
            p[i] = __expf(st0[i] - m_run);
            p[4 + i] = __expf(st1[i] - m_run);
        }
        float psum = 0.f;
#pragma unroll
        for (int i = 0; i < 8; i++) psum += p[i];
        l_part += psum;

        // pack P -> bf16 pairs; redistribute so lane (lg,lr) holds P[q=lr][key=8*lg+j]
        unsigned int u00 = (unsigned)f2bf(p[0]) | ((unsigned)f2bf(p[1]) << 16);
        unsigned int u01 = (unsigned)f2bf(p[2]) | ((unsigned)f2bf(p[3]) << 16);
        unsigned int u10 = (unsigned)f2bf(p[4]) | ((unsigned)f2bf(p[5]) << 16);
        unsigned int u11 = (unsigned)f2bf(p[6]) | ((unsigned)f2bf(p[7]) << 16);
        int sA = ((2 * lg) & 3) * 16 + lr;
        int sB = ((2 * lg + 1) & 3) * 16 + lr;
        unsigned int w0a = __shfl(u00, sA), w0b = __shfl(u10, sA);
        unsigned int w1a = __shfl(u01, sA), w1b = __shfl(u11, sA);
        unsigned int w2a = __shfl(u00, sB), w2b = __shfl(u10, sB);
        unsigned int w3a = __shfl(u01, sB), w3b = __shfl(u11, sB);
        bool hi = (lg >> 1) != 0;
        unsigned int aw0 = hi ? w0b : w0a, aw1 = hi ? w1b : w1a;
        unsigned int aw2 = hi ? w2b : w2a, aw3 = hi ? w3b : w3a;
        struct { unsigned int a, b, c, d; } awx = {aw0, aw1, aw2, aw3};
        s16x8 pa = __builtin_bit_cast(s16x8, awx);

        // O += P @ V   (V == K, from KT tile)
        __builtin_amdgcn_s_setprio(1);
#pragma unroll
        for (int nt = 0; nt < 16; nt++) {
            int d = nt * 16 + lr;
            int c = (lg ^ ((d >> 1) & 3)) * 8;
            s16x8 bv = *(const s16x8*)(&KTt[d * 32 + c]);
            o[nt] = __builtin_amdgcn_mfma_f32_16x16x32_bf16(pa, bv, o[nt], 0, 0, 0);
        }
        __builtin_amdgcn_s_setprio(0);
        __syncthreads();
    }

    // epilogue: divide by l, store bf16
    float lt = l_part + __shfl_xor(l_part, 16);
    lt += __shfl_xor(lt, 32);
    float rinv = 1.0f / lt;
    float ri[4];
#pragma unroll
    for (int r = 0; r < 4; r++) ri[r] = __shfl(rinv, lg * 4 + r);
    long orow0 = qrow0 + w * 16 + lg * 4;
#pragma unroll
    for (int nt = 0; nt < 16; nt++) {
#pragma unroll
        for (int r = 0; r < 4; r++) {
            O[(orow0 + r) * ldo + nt * 16 + lr] = f2bf(o[nt][r] * ri[r]);
        }
    }
}

// ---------------- host ----------------

extern "C" void kernel_launch(void* const* d_in, const int* in_sizes, int n_in,
                              void* d_out, int out_size, void* d_ws, size_t ws_size,
                              hipStream_t stream) {
    const float* x  = (const float*)d_in[0];
    const float* Wq = (const float*)d_in[1];
    const float* Wk = (const float*)d_in[2];
    const float* Wo = (const float*)d_in[3];
    float* out = (float*)d_out;
    char* ws = (char*)d_ws;

    unsigned short* xb  = (unsigned short*)(ws);
    unsigned short* wqt = (unsigned short*)(ws + 8388608);
    unsigned short* wkt = (unsigned short*)(ws + 9699328);
    unsigned short* wob = (unsigned short*)(ws + 11010048);
    char* dyn = ws + 12320768;

    cast_f32_bf16<<<4096, 256, 0, stream>>>(x, xb, BS_TOT * DIM);
    cast_f32_bf16<<<640, 256, 0, stream>>>(Wo, wob, DIM * HD);
    transpose_cast_w<<<dim3(8, 8, 2 * NH), 256, 0, stream>>>(Wq, Wk, wqt, wkt);

    const long perHeadElems = (long)BS_TOT * DIM;                // 4,194,304 (8MB bf16)
    const size_t FULL_NEED = 12320768ULL + 4ULL * 83886080ULL;   // ~332 MB

    if (ws_size >= FULL_NEED) {
        unsigned short* Qb  = (unsigned short*)dyn;
        unsigned short* Kb  = Qb + (long)NH * perHeadElems;
        unsigned short* Ob  = Kb + (long)NH * perHeadElems;
        unsigned short* KTb = Ob + (long)NH * perHeadElems;
        proj_kernel<<<dim3(256, NH, 2), 256, 0, stream>>>(xb, wqt, wkt, Qb, Kb, KTb,
                                                          0, perHeadElems, perHeadElems);
        attn_kernel<<<dim3(16, 16, NH), 256, 0, stream>>>(Qb, Kb, perHeadElems,
                                                          KTb, perHeadElems, Ob, HD, 256);
        final_kernel<<<dim3(256, 1, 1), 256, 0, stream>>>(Ob, HD, wob, HD, out, HD, 0);
    } else {
        unsigned short* Qh  = (unsigned short*)dyn;
        unsigned short* Kh  = Qh + perHeadElems;
        unsigned short* Oh  = Kh + perHeadElems;
        unsigned short* KTh = Oh + perHeadElems;
        hipMemsetAsync(d_out, 0, (size_t)out_size * 4, stream);
        for (int h = 0; h < NH; ++h) {
            proj_kernel<<<dim3(256, 1, 2), 256, 0, stream>>>(xb, wqt, wkt, Qh, Kh, KTh, h, 0, 0);
            attn_kernel<<<dim3(16, 16, 1), 256, 0, stream>>>(Qh, Kh, 0, KTh, 0, Oh, 256, 0);
            final_kernel<<<dim3(256, 1, 1), 256, 0, stream>>>(Oh, 256, wob + h * 256, HD, out, 256, 1);
        }
    }
}

// Round 3
// 535.949 us; speedup vs baseline: 1.9312x; 1.9312x over previous
//
#include <hip/hip_runtime.h>

typedef float f32x4 __attribute__((ext_vector_type(4)));
typedef short s16x8 __attribute__((ext_vector_type(8)));
typedef unsigned int u32;

#define BSZ 4
#define SEQ 4096
#define DIM 256
#define NH 10
#define NG 4
#define CHK 1024
#define BS_TOT 16384   // BSZ*SEQ
#define HD 2560        // NH*DIM

__device__ __forceinline__ unsigned short f2bf(float f) {
    unsigned int u = __builtin_bit_cast(unsigned int, f);
    u = (u + 0x7fffu + ((u >> 16) & 1u)) >> 16;
    return (unsigned short)u;
}

__device__ __forceinline__ void gload_lds16(const unsigned short* g, unsigned short* l) {
    __builtin_amdgcn_global_load_lds((const __attribute__((address_space(1))) u32*)g,
                                     (__attribute__((address_space(3))) u32*)l, 16, 0, 0);
}

// ---------------- cast / transpose helpers ----------------

__global__ __launch_bounds__(256) void cast_f32_bf16(const float* __restrict__ s,
                                                     unsigned short* __restrict__ d, int n) {
    long i = 4L * (blockIdx.x * 256 + threadIdx.x);
    if (i < n) {
        float4 v = *(const float4*)(s + i);
        ushort4 o;
        o.x = f2bf(v.x); o.y = f2bf(v.y); o.z = f2bf(v.z); o.w = f2bf(v.w);
        *(ushort4*)(d + i) = o;
    }
}

// Wt[h][e][d] = W[h][d][e], fp32 -> bf16.  grid (8,8,2*NH), block 256
__global__ __launch_bounds__(256) void transpose_cast_w(const float* __restrict__ Wq,
                                                        const float* __restrict__ Wk,
                                                        unsigned short* __restrict__ wqt,
                                                        unsigned short* __restrict__ wkt) {
    const float* W = (blockIdx.z & 1) ? Wk : Wq;
    unsigned short* Wt = (blockIdx.z & 1) ? wkt : wqt;
    int h = blockIdx.z >> 1;
    __shared__ float tile[32][33];
    int d0 = blockIdx.x * 32, e0 = blockIdx.y * 32;
    int tx = threadIdx.x & 31, ty = threadIdx.x >> 5;
    const float* Wh = W + (long)h * 65536;
    unsigned short* Wth = Wt + (long)h * 65536;
#pragma unroll
    for (int r = ty; r < 32; r += 8) tile[r][tx] = Wh[(long)(d0 + r) * 256 + e0 + tx];
    __syncthreads();
#pragma unroll
    for (int r = ty; r < 32; r += 8) Wth[(long)(e0 + r) * 256 + d0 + tx] = f2bf(tile[tx][r]);
}

// ---------------- generic C[m][n] = sum_k A[m][k] * Bt[n][k], N=256 ----------------
// block 256 thr (4 waves), M-tile 64 (wave w: rows 16w..16w+15)
// Optional KTo: transposed bf16 store KTo[bg][col][key] (bg = m>>10, key = m&1023)

__device__ __forceinline__ void gemm_body(const unsigned short* __restrict__ A, long lda,
                                          const unsigned short* __restrict__ Bt, long ldb,
                                          unsigned short* Cb, float* Cf, long ldc,
                                          int K, bool accum, long mbase,
                                          unsigned short* KTo) {
    __shared__ unsigned short As[64 * 40];
    __shared__ unsigned short Bs[256 * 40];
    const int t = threadIdx.x;
    const int w = t >> 6, l = t & 63, lr = l & 15, lg = l >> 4;

    f32x4 acc[16];
#pragma unroll
    for (int i = 0; i < 16; i++) acc[i] = (f32x4){0.f, 0.f, 0.f, 0.f};

    const int ar = t >> 2, akc = (t & 3) * 8;

    for (int k0 = 0; k0 < K; k0 += 32) {
        *(s16x8*)(&As[ar * 40 + akc]) = *(const s16x8*)(A + (mbase + ar) * lda + k0 + akc);
#pragma unroll
        for (int s = 0; s < 4; s++) {
            int n = s * 64 + (t >> 2);
            *(s16x8*)(&Bs[n * 40 + akc]) = *(const s16x8*)(Bt + (long)n * ldb + k0 + akc);
        }
        __syncthreads();
        s16x8 af = *(const s16x8*)(&As[(w * 16 + lr) * 40 + lg * 8]);
        __builtin_amdgcn_s_setprio(1);
#pragma unroll
        for (int nt = 0; nt < 16; nt++) {
            s16x8 bf = *(const s16x8*)(&Bs[(nt * 16 + lr) * 40 + lg * 8]);
            acc[nt] = __builtin_amdgcn_mfma_f32_16x16x32_bf16(af, bf, acc[nt], 0, 0, 0);
        }
        __builtin_amdgcn_s_setprio(0);
        __syncthreads();
    }
    long m0 = mbase + w * 16 + lg * 4;
#pragma unroll
    for (int nt = 0; nt < 16; nt++) {
        int col = nt * 16 + lr;
#pragma unroll
        for (int r = 0; r < 4; r++) {
            long idx = (m0 + r) * ldc + col;
            if (Cb) {
                Cb[idx] = f2bf(acc[nt][r]);
            } else {
                float v = acc[nt][r];
                if (accum) v += Cf[idx];
                Cf[idx] = v;
            }
        }
    }
    if (KTo) {
        int bg = (int)(m0 >> 10);
        int key0 = (int)(m0 & 1023);
        unsigned short* base = KTo + ((long)bg * 256) * 1024 + key0;
#pragma unroll
        for (int nt = 0; nt < 16; nt++) {
            int col = nt * 16 + lr;
            ushort4 v;
            v.x = f2bf(acc[nt][0]); v.y = f2bf(acc[nt][1]);
            v.z = f2bf(acc[nt][2]); v.w = f2bf(acc[nt][3]);
            *(ushort4*)(base + (long)col * 1024) = v;
        }
    }
}

// grid (256, nh, 2)
__global__ __launch_bounds__(256) void proj_kernel(const unsigned short* __restrict__ xb,
                                                   const unsigned short* __restrict__ wqt,
                                                   const unsigned short* __restrict__ wkt,
                                                   unsigned short* Qb, unsigned short* Kb,
                                                   unsigned short* KTb,
                                                   int h0, long headStrideOut, long headStrideKT) {
    int h = h0 + blockIdx.y;
    bool isK = (blockIdx.z != 0);
    const unsigned short* Bt = (isK ? wkt : wqt) + (long)h * 65536;
    unsigned short* C = (isK ? Kb : Qb) + (long)blockIdx.y * headStrideOut;
    unsigned short* KTo = isK ? (KTb + (long)blockIdx.y * headStrideKT) : nullptr;
    gemm_body(xb, 256, Bt, 256, C, nullptr, 256, 256, false, (long)blockIdx.x * 64, KTo);
}

// per-head fallback final: C[m][0..256) += A[m][k]*Bt[n][k], K=256
__global__ __launch_bounds__(256) void final_kernel(const unsigned short* __restrict__ Ob, long lda,
                                                    const unsigned short* __restrict__ wob, long ldb,
                                                    float* out, int K, int accum) {
    gemm_body(Ob, lda, wob, ldb, nullptr, out, 256, K, accum != 0, (long)blockIdx.x * 64, nullptr);
}

// full-path final: A is head-strided O (=Qb alias): A[m][k] = Ob[(k>>8)*hs + m*256 + (k&255)]
// out[m][n] = sum_k A[m][k] * wob[n][k], n in [0,256), k in [0,2560). grid 256.
__global__ __launch_bounds__(256) void final_full(const unsigned short* __restrict__ Ob,
                                                  long headStride,
                                                  const unsigned short* __restrict__ wob,
                                                  float* __restrict__ out) {
    __shared__ unsigned short As[64 * 40];
    __shared__ unsigned short Bs[256 * 40];
    const int t = threadIdx.x;
    const int w = t >> 6, l = t & 63, lr = l & 15, lg = l >> 4;
    const long mbase = (long)blockIdx.x * 64;

    f32x4 acc[16];
#pragma unroll
    for (int i = 0; i < 16; i++) acc[i] = (f32x4){0.f, 0.f, 0.f, 0.f};

    const int ar = t >> 2, akc = (t & 3) * 8;

    for (int k0 = 0; k0 < HD; k0 += 32) {
        const unsigned short* Asrc = Ob + (long)(k0 >> 8) * headStride + (k0 & 255);
        *(s16x8*)(&As[ar * 40 + akc]) = *(const s16x8*)(Asrc + (mbase + ar) * 256 + akc);
#pragma unroll
        for (int s = 0; s < 4; s++) {
            int n = s * 64 + (t >> 2);
            *(s16x8*)(&Bs[n * 40 + akc]) = *(const s16x8*)(wob + (long)n * HD + k0 + akc);
        }
        __syncthreads();
        s16x8 af = *(const s16x8*)(&As[(w * 16 + lr) * 40 + lg * 8]);
        __builtin_amdgcn_s_setprio(1);
#pragma unroll
        for (int nt = 0; nt < 16; nt++) {
            s16x8 bf = *(const s16x8*)(&Bs[(nt * 16 + lr) * 40 + lg * 8]);
            acc[nt] = __builtin_amdgcn_mfma_f32_16x16x32_bf16(af, bf, acc[nt], 0, 0, 0);
        }
        __builtin_amdgcn_s_setprio(0);
        __syncthreads();
    }
    long m0 = mbase + w * 16 + lg * 4;
#pragma unroll
    for (int nt = 0; nt < 16; nt++) {
        int col = nt * 16 + lr;
#pragma unroll
        for (int r = 0; r < 4; r++) out[(m0 + r) * 256 + col] = acc[nt][r];
    }
}

// ---------------- attention ----------------
// 1D grid (nblk), block 256. XCD-chunked swizzle: logical = (lb&7)*chunkPerXcd + (lb>>3).
// logical -> bx (q-tile, 16) | by (b*4+g, 16) | h.  wave w: q rows [64*bx + 16w, +16)
// chunk g attends KV chunk (g+1)%4.  V == K.
// Krm: [32 keys][256 d] with 16B-chunk slots XOR'd by (row&7)     (QK^T A-frags)
// KTt: [256 d][32 keys] with 16B-chunk slots XOR'd by ((d>>1)&3)  (PV B-frags)

__global__ __launch_bounds__(256) void attn_kernel(const unsigned short* __restrict__ Qb,
                                                   const unsigned short* __restrict__ Kb,
                                                   long headStrideQK,
                                                   const unsigned short* __restrict__ KTg,
                                                   long headStrideKT,
                                                   unsigned short* __restrict__ Ob,
                                                   long ldo, long colStride,
                                                   int chunkPerXcd) {
    const int lb = blockIdx.x;
    const int logical = (lb & 7) * chunkPerXcd + (lb >> 3);
    const int bx = logical & 15;
    const int by = (logical >> 4) & 15;
    const int h = logical >> 8;

    const unsigned short* Q = Qb + (long)h * headStrideQK;
    const unsigned short* Kp = Kb + (long)h * headStrideQK;
    const unsigned short* KT = KTg + (long)h * headStrideKT;
    unsigned short* O = Ob + (long)h * colStride;
    const int b = by >> 2, g = by & 3;
    const long qrow0 = (long)b * SEQ + (long)g * CHK + (long)bx * 64;
    const long krow0 = (long)b * SEQ + (long)((g + 1) & 3) * CHK;
    const unsigned short* KTc = KT + ((long)(b * NG + ((g + 1) & 3)) * 256) * 1024;

    __shared__ unsigned short Krm[32 * 256];  // 16KB
    __shared__ unsigned short KTt[256 * 32];  // 16KB

    const int t = threadIdx.x;
    const int w = t >> 6, l = t & 63, lr = l & 15, lg = l >> 4;

    // Q fragments: lane holds Q[q=lr][d = s*32 + lg*8 + j]  (read BEFORE any O write)
    s16x8 qf[8];
    {
        const unsigned short* qp = Q + (qrow0 + w * 16 + lr) * 256 + lg * 8;
#pragma unroll
        for (int s = 0; s < 8; s++) qf[s] = *(const s16x8*)(qp + s * 32);
    }

    f32x4 o[16];
#pragma unroll
    for (int i = 0; i < 16; i++) o[i] = (f32x4){0.f, 0.f, 0.f, 0.f};
    float m_run = -1e30f, l_part = 0.f;

    // staging lane decomposition (per-wave global_load_lds, linear LDS dest)
    const int kA_row = l >> 5, kA_slot = l & 31;   // Krm: 2 rows x 32 slots per inst
    const int kT_roff = l >> 2, kT_slot = l & 3;   // KTt: 16 rows x 4 slots per inst

    for (int kt = 0; kt < 32; ++kt) {
        const unsigned short* Ksrc = Kp + (krow0 + kt * 32) * 256;
        const unsigned short* Tsrc = KTc + kt * 32;
#pragma unroll
        for (int i = 0; i < 4; i++) {
            int rb = w * 8 + i * 2;
            int row = rb + kA_row;
            int c = kA_slot ^ (row & 7);
            gload_lds16(Ksrc + row * 256 + c * 8, &Krm[rb * 256]);
        }
#pragma unroll
        for (int i = 0; i < 4; i++) {
            int rb = w * 64 + i * 16;
            int row = rb + kT_roff;
            int c = kT_slot ^ ((row >> 1) & 3);
            gload_lds16(Tsrc + (long)row * 1024 + c * 8, &KTt[rb * 32]);
        }
        __syncthreads();

        // St = K_tile @ Q^T : lane owns q=lr (col), keys lg*4 + r (st0) / 16+lg*4+r (st1)
        f32x4 st0 = (f32x4){0.f, 0.f, 0.f, 0.f}, st1 = st0;
        __builtin_amdgcn_s_setprio(1);
#pragma unroll
        for (int s = 0; s < 8; s++) {
            int c0 = ((s * 4 + lg) ^ (lr & 7)) * 8;
            s16x8 a0 = *(const s16x8*)(&Krm[lr * 256 + c0]);
            s16x8 a1 = *(const s16x8*)(&Krm[(16 + lr) * 256 + c0]);
            st0 = __builtin_amdgcn_mfma_f32_16x16x32_bf16(a0, qf[s], st0, 0, 0, 0);
            st1 = __builtin_amdgcn_mfma_f32_16x16x32_bf16(a1, qf[s], st1, 0, 0, 0);
        }
        __builtin_amdgcn_s_setprio(0);

        // online softmax for q = lr, defer-max (THR=8)
        float vmax = fmaxf(fmaxf(fmaxf(st0[0], st0[1]), fmaxf(st0[2], st0[3])),
                           fmaxf(fmaxf(st1[0], st1[1]), fmaxf(st1[2], st1[3])));
        vmax = fmaxf(vmax, __shfl_xor(vmax, 16));
        vmax = fmaxf(vmax, __shfl_xor(vmax, 32));
        if (!__all(vmax <= m_run + 8.0f)) {
            float m_new = fmaxf(m_run, vmax);
            float scale = __expf(m_run - m_new);
            m_run = m_new;
            l_part *= scale;
            float sc[4];
#pragma unroll
            for (int r = 0; r < 4; r++) sc[r] = __shfl(scale, lg * 4 + r);
#pragma unroll
            for (int nt = 0; nt < 16; nt++) {
                o[nt][0] *= sc[0]; o[nt][1] *= sc[1]; o[nt][2] *= sc[2]; o[nt][3] *= sc[3];
            }
        }
        float p[8];
#pragma unroll
        for (int i = 0; i < 4; i++) {
            p[i] = __expf(st0[i] - m_run);
            p[4 + i] = __expf(st1[i] - m_run);
        }
        float psum = 0.f;
#pragma unroll
        for (int i = 0; i < 8; i++) psum += p[i];
        l_part += psum;

        // pack P -> bf16 pairs; redistribute so lane (lg,lr) holds P[q=lr][key=8*lg+j]
        unsigned int u00 = (unsigned)f2bf(p[0]) | ((unsigned)f2bf(p[1]) << 16);
        unsigned int u01 = (unsigned)f2bf(p[2]) | ((unsigned)f2bf(p[3]) << 16);
        unsigned int u10 = (unsigned)f2bf(p[4]) | ((unsigned)f2bf(p[5]) << 16);
        unsigned int u11 = (unsigned)f2bf(p[6]) | ((unsigned)f2bf(p[7]) << 16);
        int sA = ((2 * lg) & 3) * 16 + lr;
        int sB = ((2 * lg + 1) & 3) * 16 + lr;
        unsigned int w0a = __shfl(u00, sA), w0b = __shfl(u10, sA);
        unsigned int w1a = __shfl(u01, sA), w1b = __shfl(u11, sA);
        unsigned int w2a = __shfl(u00, sB), w2b = __shfl(u10, sB);
        unsigned int w3a = __shfl(u01, sB), w3b = __shfl(u11, sB);
        bool hi = (lg >> 1) != 0;
        unsigned int aw0 = hi ? w0b : w0a, aw1 = hi ? w1b : w1a;
        unsigned int aw2 = hi ? w2b : w2a, aw3 = hi ? w3b : w3a;
        struct { unsigned int a, b, c, d; } awx = {aw0, aw1, aw2, aw3};
        s16x8 pa = __builtin_bit_cast(s16x8, awx);

        // O += P @ V   (V == K, from KT tile)
        __builtin_amdgcn_s_setprio(1);
#pragma unroll
        for (int nt = 0; nt < 16; nt++) {
            int d = nt * 16 + lr;
            int c = (lg ^ ((d >> 1) & 3)) * 8;
            s16x8 bv = *(const s16x8*)(&KTt[d * 32 + c]);
            o[nt] = __builtin_amdgcn_mfma_f32_16x16x32_bf16(pa, bv, o[nt], 0, 0, 0);
        }
        __builtin_amdgcn_s_setprio(0);
        __syncthreads();
    }

    // epilogue: divide by l, store bf16
    float lt = l_part + __shfl_xor(l_part, 16);
    lt += __shfl_xor(lt, 32);
    float rinv = 1.0f / lt;
    float ri[4];
#pragma unroll
    for (int r = 0; r < 4; r++) ri[r] = __shfl(rinv, lg * 4 + r);
    long orow0 = qrow0 + w * 16 + lg * 4;
#pragma unroll
    for (int nt = 0; nt < 16; nt++) {
#pragma unroll
        for (int r = 0; r < 4; r++) {
            O[(orow0 + r) * ldo + nt * 16 + lr] = f2bf(o[nt][r] * ri[r]);
        }
    }
}

// ---------------- host ----------------

extern "C" void kernel_launch(void* const* d_in, const int* in_sizes, int n_in,
                              void* d_out, int out_size, void* d_ws, size_t ws_size,
                              hipStream_t stream) {
    const float* x  = (const float*)d_in[0];
    const float* Wq = (const float*)d_in[1];
    const float* Wk = (const float*)d_in[2];
    const float* Wo = (const float*)d_in[3];
    float* out = (float*)d_out;
    char* ws = (char*)d_ws;

    unsigned short* xb  = (unsigned short*)(ws);
    unsigned short* wqt = (unsigned short*)(ws + 8388608);
    unsigned short* wkt = (unsigned short*)(ws + 9699328);
    unsigned short* wob = (unsigned short*)(ws + 11010048);
    char* dyn = ws + 12320768;

    cast_f32_bf16<<<4096, 256, 0, stream>>>(x, xb, BS_TOT * DIM);
    cast_f32_bf16<<<640, 256, 0, stream>>>(Wo, wob, DIM * HD);
    transpose_cast_w<<<dim3(8, 8, 2 * NH), 256, 0, stream>>>(Wq, Wk, wqt, wkt);

    const long perHeadElems = (long)BS_TOT * DIM;                // 4,194,304 (8MB bf16)
    const size_t FULL_NEED = 12320768ULL + 3ULL * 83886080ULL;   // ~264 MB (round-1 proven)

    if (ws_size >= FULL_NEED) {
        unsigned short* Qb  = (unsigned short*)dyn;              // also O (aliased)
        unsigned short* Kb  = Qb + (long)NH * perHeadElems;
        unsigned short* KTb = Kb + (long)NH * perHeadElems;
        proj_kernel<<<dim3(256, NH, 2), 256, 0, stream>>>(xb, wqt, wkt, Qb, Kb, KTb,
                                                          0, perHeadElems, perHeadElems);
        // O overwrites Q in-place (per-head-major), 2560 blocks XCD-chunked (2560/8=320)
        attn_kernel<<<2560, 256, 0, stream>>>(Qb, Kb, perHeadElems, KTb, perHeadElems,
                                              Qb, 256, perHeadElems, 320);
        final_full<<<256, 256, 0, stream>>>(Qb, perHeadElems, wob, out);
    } else {
        unsigned short* Qh  = (unsigned short*)dyn;              // also O (aliased)
        unsigned short* Kh  = Qh + perHeadElems;
        unsigned short* KTh = Kh + perHeadElems;
        hipMemsetAsync(d_out, 0, (size_t)out_size * 4, stream);
        for (int h = 0; h < NH; ++h) {
            proj_kernel<<<dim3(256, 1, 2), 256, 0, stream>>>(xb, wqt, wkt, Qh, Kh, KTh, h, 0, 0);
            attn_kernel<<<256, 256, 0, stream>>>(Qh, Kh, 0, KTh, 0, Qh, 256, 0, 32);
            final_kernel<<<256, 256, 0, stream>>>(Qh, 256, wob + h * 256, HD, out, 256, 1);
        }
    }
}

// Round 4
// 521.079 us; speedup vs baseline: 1.9863x; 1.0285x over previous
//
#include <hip/hip_runtime.h>

typedef float f32x4 __attribute__((ext_vector_type(4)));
typedef short s16x8 __attribute__((ext_vector_type(8)));
typedef unsigned int u32;

#define BSZ 4
#define SEQ 4096
#define DIM 256
#define NH 10
#define NG 4
#define CHK 1024
#define BS_TOT 16384   // BSZ*SEQ
#define HD 2560        // NH*DIM

__device__ __forceinline__ unsigned short f2bf(float f) {
    unsigned int u = __builtin_bit_cast(unsigned int, f);
    u = (u + 0x7fffu + ((u >> 16) & 1u)) >> 16;
    return (unsigned short)u;
}

__device__ __forceinline__ void gload_lds16(const unsigned short* g, unsigned short* l) {
    __builtin_amdgcn_global_load_lds((const __attribute__((address_space(1))) u32*)g,
                                     (__attribute__((address_space(3))) u32*)l, 16, 0, 0);
}

// ---------------- cast / transpose helpers ----------------

__global__ __launch_bounds__(256) void cast_f32_bf16(const float* __restrict__ s,
                                                     unsigned short* __restrict__ d, int n) {
    long i = 4L * (blockIdx.x * 256 + threadIdx.x);
    if (i < n) {
        float4 v = *(const float4*)(s + i);
        ushort4 o;
        o.x = f2bf(v.x); o.y = f2bf(v.y); o.z = f2bf(v.z); o.w = f2bf(v.w);
        *(ushort4*)(d + i) = o;
    }
}

// Wt[h][e][d] = W[h][d][e], fp32 -> bf16.  grid (8,8,2*NH), block 256
__global__ __launch_bounds__(256) void transpose_cast_w(const float* __restrict__ Wq,
                                                        const float* __restrict__ Wk,
                                                        unsigned short* __restrict__ wqt,
                                                        unsigned short* __restrict__ wkt) {
    const float* W = (blockIdx.z & 1) ? Wk : Wq;
    unsigned short* Wt = (blockIdx.z & 1) ? wkt : wqt;
    int h = blockIdx.z >> 1;
    __shared__ float tile[32][33];
    int d0 = blockIdx.x * 32, e0 = blockIdx.y * 32;
    int tx = threadIdx.x & 31, ty = threadIdx.x >> 5;
    const float* Wh = W + (long)h * 65536;
    unsigned short* Wth = Wt + (long)h * 65536;
#pragma unroll
    for (int r = ty; r < 32; r += 8) tile[r][tx] = Wh[(long)(d0 + r) * 256 + e0 + tx];
    __syncthreads();
#pragma unroll
    for (int r = ty; r < 32; r += 8) Wth[(long)(e0 + r) * 256 + d0 + tx] = f2bf(tile[tx][r]);
}

// ---------------- generic C[m][n] = sum_k A[m][k] * Bt[n][k], N=256 ----------------
// block 256 thr (4 waves), M-tile 64 (wave w: rows 16w..16w+15)
// Optional KTo: transposed bf16 store, key-tile-chunked: KTo[bg][key>>5][col][key&31]

__device__ __forceinline__ void gemm_body(const unsigned short* __restrict__ A, long lda,
                                          const unsigned short* __restrict__ Bt, long ldb,
                                          unsigned short* Cb, float* Cf, long ldc,
                                          int K, bool accum, long mbase,
                                          unsigned short* KTo) {
    __shared__ unsigned short As[64 * 40];
    __shared__ unsigned short Bs[256 * 40];
    const int t = threadIdx.x;
    const int w = t >> 6, l = t & 63, lr = l & 15, lg = l >> 4;

    f32x4 acc[16];
#pragma unroll
    for (int i = 0; i < 16; i++) acc[i] = (f32x4){0.f, 0.f, 0.f, 0.f};

    const int ar = t >> 2, akc = (t & 3) * 8;

    for (int k0 = 0; k0 < K; k0 += 32) {
        *(s16x8*)(&As[ar * 40 + akc]) = *(const s16x8*)(A + (mbase + ar) * lda + k0 + akc);
#pragma unroll
        for (int s = 0; s < 4; s++) {
            int n = s * 64 + (t >> 2);
            *(s16x8*)(&Bs[n * 40 + akc]) = *(const s16x8*)(Bt + (long)n * ldb + k0 + akc);
        }
        __syncthreads();
        s16x8 af = *(const s16x8*)(&As[(w * 16 + lr) * 40 + lg * 8]);
        __builtin_amdgcn_s_setprio(1);
#pragma unroll
        for (int nt = 0; nt < 16; nt++) {
            s16x8 bf = *(const s16x8*)(&Bs[(nt * 16 + lr) * 40 + lg * 8]);
            acc[nt] = __builtin_amdgcn_mfma_f32_16x16x32_bf16(af, bf, acc[nt], 0, 0, 0);
        }
        __builtin_amdgcn_s_setprio(0);
        __syncthreads();
    }
    long m0 = mbase + w * 16 + lg * 4;
#pragma unroll
    for (int nt = 0; nt < 16; nt++) {
        int col = nt * 16 + lr;
#pragma unroll
        for (int r = 0; r < 4; r++) {
            long idx = (m0 + r) * ldc + col;
            if (Cb) {
                Cb[idx] = f2bf(acc[nt][r]);
            } else {
                float v = acc[nt][r];
                if (accum) v += Cf[idx];
                Cf[idx] = v;
            }
        }
    }
    if (KTo) {
        int bg = (int)(m0 >> 10);
        int key0 = (int)(m0 & 1023);
        // chunked: tile kt = key0>>5 holds [256 d][32 keys] contiguous (16KB)
        unsigned short* base = KTo + (long)bg * (256 * 1024)
                             + (long)(key0 >> 5) * (256 * 32) + (key0 & 31);
#pragma unroll
        for (int nt = 0; nt < 16; nt++) {
            int col = nt * 16 + lr;
            ushort4 v;
            v.x = f2bf(acc[nt][0]); v.y = f2bf(acc[nt][1]);
            v.z = f2bf(acc[nt][2]); v.w = f2bf(acc[nt][3]);
            *(ushort4*)(base + (long)col * 32) = v;
        }
    }
}

// grid (256, nh, 2)
__global__ __launch_bounds__(256) void proj_kernel(const unsigned short* __restrict__ xb,
                                                   const unsigned short* __restrict__ wqt,
                                                   const unsigned short* __restrict__ wkt,
                                                   unsigned short* Qb, unsigned short* Kb,
                                                   unsigned short* KTb,
                                                   int h0, long headStrideOut, long headStrideKT) {
    int h = h0 + blockIdx.y;
    bool isK = (blockIdx.z != 0);
    const unsigned short* Bt = (isK ? wkt : wqt) + (long)h * 65536;
    unsigned short* C = (isK ? Kb : Qb) + (long)blockIdx.y * headStrideOut;
    unsigned short* KTo = isK ? (KTb + (long)blockIdx.y * headStrideKT) : nullptr;
    gemm_body(xb, 256, Bt, 256, C, nullptr, 256, 256, false, (long)blockIdx.x * 64, KTo);
}

// per-head fallback final: C[m][0..256) += A[m][k]*Bt[n][k], K=256
__global__ __launch_bounds__(256) void final_kernel(const unsigned short* __restrict__ Ob, long lda,
                                                    const unsigned short* __restrict__ wob, long ldb,
                                                    float* out, int K, int accum) {
    gemm_body(Ob, lda, wob, ldb, nullptr, out, 256, K, accum != 0, (long)blockIdx.x * 64, nullptr);
}

// full-path final: A is head-strided O (=Qb alias): A[m][k] = Ob[(k>>8)*hs + m*256 + (k&255)]
// out[m][n] = sum_k A[m][k] * wob[n][k], n in [0,256), k in [0,2560). grid 256.
__global__ __launch_bounds__(256) void final_full(const unsigned short* __restrict__ Ob,
                                                  long headStride,
                                                  const unsigned short* __restrict__ wob,
                                                  float* __restrict__ out) {
    __shared__ unsigned short As[64 * 40];
    __shared__ unsigned short Bs[256 * 40];
    const int t = threadIdx.x;
    const int w = t >> 6, l = t & 63, lr = l & 15, lg = l >> 4;
    const long mbase = (long)blockIdx.x * 64;

    f32x4 acc[16];
#pragma unroll
    for (int i = 0; i < 16; i++) acc[i] = (f32x4){0.f, 0.f, 0.f, 0.f};

    const int ar = t >> 2, akc = (t & 3) * 8;

    for (int k0 = 0; k0 < HD; k0 += 32) {
        const unsigned short* Asrc = Ob + (long)(k0 >> 8) * headStride + (k0 & 255);
        *(s16x8*)(&As[ar * 40 + akc]) = *(const s16x8*)(Asrc + (mbase + ar) * 256 + akc);
#pragma unroll
        for (int s = 0; s < 4; s++) {
            int n = s * 64 + (t >> 2);
            *(s16x8*)(&Bs[n * 40 + akc]) = *(const s16x8*)(wob + (long)n * HD + k0 + akc);
        }
        __syncthreads();
        s16x8 af = *(const s16x8*)(&As[(w * 16 + lr) * 40 + lg * 8]);
        __builtin_amdgcn_s_setprio(1);
#pragma unroll
        for (int nt = 0; nt < 16; nt++) {
            s16x8 bf = *(const s16x8*)(&Bs[(nt * 16 + lr) * 40 + lg * 8]);
            acc[nt] = __builtin_amdgcn_mfma_f32_16x16x32_bf16(af, bf, acc[nt], 0, 0, 0);
        }
        __builtin_amdgcn_s_setprio(0);
        __syncthreads();
    }
    long m0 = mbase + w * 16 + lg * 4;
#pragma unroll
    for (int nt = 0; nt < 16; nt++) {
        int col = nt * 16 + lr;
#pragma unroll
        for (int r = 0; r < 4; r++) out[(m0 + r) * 256 + col] = acc[nt][r];
    }
}

// ---------------- attention ----------------
// 1D grid (nblk), block 256. XCD-chunked swizzle: logical = (lb&7)*chunkPerXcd + (lb>>3).
// logical -> bx (q-tile, 16) | by (b*4+g, 16) | h.  wave w: q rows [64*bx + 16w, +16)
// chunk g attends KV chunk (g+1)%4.  V == K.
// Double-buffered 2-phase: STAGE(t+1) issued before compute(t); one barrier/tile.
// Krm: [32 keys][256 d], 16B slots XOR'd by (row&7)      (QK^T A-frags)
// KTt: [256 d][32 keys], 16B slots XOR'd by ((d>>1)&3)   (PV B-frags); KT global is
//      key-tile-chunked so each tile is one contiguous 16KB block.

__global__ __launch_bounds__(256) void attn_kernel(const unsigned short* __restrict__ Qb,
                                                   const unsigned short* __restrict__ Kb,
                                                   long headStrideQK,
                                                   const unsigned short* __restrict__ KTg,
                                                   long headStrideKT,
                                                   unsigned short* __restrict__ Ob,
                                                   long ldo, long colStride,
                                                   int chunkPerXcd) {
    const int lb = blockIdx.x;
    const int logical = (lb & 7) * chunkPerXcd + (lb >> 3);
    const int bx = logical & 15;
    const int by = (logical >> 4) & 15;
    const int h = logical >> 8;

    const unsigned short* Q = Qb + (long)h * headStrideQK;
    const unsigned short* Kp = Kb + (long)h * headStrideQK;
    const unsigned short* KT = KTg + (long)h * headStrideKT;
    unsigned short* O = Ob + (long)h * colStride;
    const int b = by >> 2, g = by & 3;
    const long qrow0 = (long)b * SEQ + (long)g * CHK + (long)bx * 64;
    const long krow0 = (long)b * SEQ + (long)((g + 1) & 3) * CHK;
    const unsigned short* KTc = KT + (long)(b * NG + ((g + 1) & 3)) * (256 * 1024);

    __shared__ unsigned short Krm[2][32 * 256];  // 2 x 16KB
    __shared__ unsigned short KTt[2][256 * 32];  // 2 x 16KB

    const int t = threadIdx.x;
    const int w = t >> 6, l = t & 63, lr = l & 15, lg = l >> 4;

    // Q fragments: lane holds Q[q=lr][d = s*32 + lg*8 + j]  (read BEFORE any O write)
    s16x8 qf[8];
    {
        const unsigned short* qp = Q + (qrow0 + w * 16 + lr) * 256 + lg * 8;
#pragma unroll
        for (int s = 0; s < 8; s++) qf[s] = *(const s16x8*)(qp + s * 32);
    }

    f32x4 o[16];
#pragma unroll
    for (int i = 0; i < 16; i++) o[i] = (f32x4){0.f, 0.f, 0.f, 0.f};
    float m_run = -1e30f, l_part = 0.f;

    // staging lane decomposition (per-wave global_load_lds, linear LDS dest)
    const int kA_row = l >> 5, kA_slot = l & 31;   // Krm: 2 rows x 32 slots per inst
    const int kT_roff = l >> 2, kT_slot = l & 3;   // KTt: 16 rows x 4 slots per inst

#define STAGE(buf, kt_) do {                                                    \
        const unsigned short* Ksrc = Kp + (krow0 + (long)(kt_) * 32) * 256;     \
        const unsigned short* Tsrc = KTc + (long)(kt_) * (32 * 256);            \
        _Pragma("unroll")                                                       \
        for (int i = 0; i < 4; i++) {                                           \
            int rb = w * 8 + i * 2;                                             \
            int row = rb + kA_row;                                              \
            int c = kA_slot ^ (row & 7);                                        \
            gload_lds16(Ksrc + row * 256 + c * 8, &Krm[buf][rb * 256]);         \
        }                                                                       \
        _Pragma("unroll")                                                       \
        for (int i = 0; i < 4; i++) {                                           \
            int rb = w * 64 + i * 16;                                           \
            int row = rb + kT_roff;                                             \
            int c = kT_slot ^ ((row >> 1) & 3);                                 \
            gload_lds16(Tsrc + (long)row * 32 + c * 8, &KTt[buf][rb * 32]);     \
        }                                                                       \
    } while (0)

    STAGE(0, 0);
    __syncthreads();
    int cur = 0;

    for (int kt = 0; kt < 32; ++kt) {
        if (kt < 31) STAGE(cur ^ 1, kt + 1);   // prefetch next tile (hidden under compute)

        // St = K_tile @ Q^T : lane owns q=lr (col), keys lg*4 + r (st0) / 16+lg*4+r (st1)
        f32x4 st0 = (f32x4){0.f, 0.f, 0.f, 0.f}, st1 = st0;
        __builtin_amdgcn_s_setprio(1);
#pragma unroll
        for (int s = 0; s < 8; s++) {
            int c0 = ((s * 4 + lg) ^ (lr & 7)) * 8;
            s16x8 a0 = *(const s16x8*)(&Krm[cur][lr * 256 + c0]);
            s16x8 a1 = *(const s16x8*)(&Krm[cur][(16 + lr) * 256 + c0]);
            st0 = __builtin_amdgcn_mfma_f32_16x16x32_bf16(a0, qf[s], st0, 0, 0, 0);
            st1 = __builtin_amdgcn_mfma_f32_16x16x32_bf16(a1, qf[s], st1, 0, 0, 0);
        }
        __builtin_amdgcn_s_setprio(0);

        // online softmax for q = lr, defer-max (THR=8)
        float vmax = fmaxf(fmaxf(fmaxf(st0[0], st0[1]), fmaxf(st0[2], st0[3])),
                           fmaxf(fmaxf(st1[0], st1[1]), fmaxf(st1[2], st1[3])));
        vmax = fmaxf(vmax, __shfl_xor(vmax, 16));
        vmax = fmaxf(vmax, __shfl_xor(vmax, 32));
        if (!__all(vmax <= m_run + 8.0f)) {
            float m_new = fmaxf(m_run, vmax);
            float scale = __expf(m_run - m_new);
            m_run = m_new;
            l_part *= scale;
            float sc[4];
#pragma unroll
            for (int r = 0; r < 4; r++) sc[r] = __shfl(scale, lg * 4 + r);
#pragma unroll
            for (int nt = 0; nt < 16; nt++) {
                o[nt][0] *= sc[0]; o[nt][1] *= sc[1]; o[nt][2] *= sc[2]; o[nt][3] *= sc[3];
            }
        }
        float p[8];
#pragma unroll
        for (int i = 0; i < 4; i++) {
            p[i] = __expf(st0[i] - m_run);
            p[4 + i] = __expf(st1[i] - m_run);
        }
        float psum = 0.f;
#pragma unroll
        for (int i = 0; i < 8; i++) psum += p[i];
        l_part += psum;

        // pack P -> bf16 pairs; redistribute so lane (lg,lr) holds P[q=lr][key=8*lg+j]
        unsigned int u00 = (unsigned)f2bf(p[0]) | ((unsigned)f2bf(p[1]) << 16);
        unsigned int u01 = (unsigned)f2bf(p[2]) | ((unsigned)f2bf(p[3]) << 16);
        unsigned int u10 = (unsigned)f2bf(p[4]) | ((unsigned)f2bf(p[5]) << 16);
        unsigned int u11 = (unsigned)f2bf(p[6]) | ((unsigned)f2bf(p[7]) << 16);
        int sA = ((2 * lg) & 3) * 16 + lr;
        int sB = ((2 * lg + 1) & 3) * 16 + lr;
        unsigned int w0a = __shfl(u00, sA), w0b = __shfl(u10, sA);
        unsigned int w1a = __shfl(u01, sA), w1b = __shfl(u11, sA);
        unsigned int w2a = __shfl(u00, sB), w2b = __shfl(u10, sB);
        unsigned int w3a = __shfl(u01, sB), w3b = __shfl(u11, sB);
        bool hi = (lg >> 1) != 0;
        unsigned int aw0 = hi ? w0b : w0a, aw1 = hi ? w1b : w1a;
        unsigned int aw2 = hi ? w2b : w2a, aw3 = hi ? w3b : w3a;
        struct { unsigned int a, b, c, d; } awx = {aw0, aw1, aw2, aw3};
        s16x8 pa = __builtin_bit_cast(s16x8, awx);

        // O += P @ V   (V == K, from KT tile)
        __builtin_amdgcn_s_setprio(1);
#pragma unroll
        for (int nt = 0; nt < 16; nt++) {
            int d = nt * 16 + lr;
            int c = (lg ^ ((d >> 1) & 3)) * 8;
            s16x8 bv = *(const s16x8*)(&KTt[cur][d * 32 + c]);
            o[nt] = __builtin_amdgcn_mfma_f32_16x16x32_bf16(pa, bv, o[nt], 0, 0, 0);
        }
        __builtin_amdgcn_s_setprio(0);

        __syncthreads();   // drains vmcnt(0): next tile's loads complete; cur reusable
        cur ^= 1;
    }
#undef STAGE

    // epilogue: divide by l, store bf16
    float lt = l_part + __shfl_xor(l_part, 16);
    lt += __shfl_xor(lt, 32);
    float rinv = 1.0f / lt;
    float ri[4];
#pragma unroll
    for (int r = 0; r < 4; r++) ri[r] = __shfl(rinv, lg * 4 + r);
    long orow0 = qrow0 + w * 16 + lg * 4;
#pragma unroll
    for (int nt = 0; nt < 16; nt++) {
#pragma unroll
        for (int r = 0; r < 4; r++) {
            O[(orow0 + r) * ldo + nt * 16 + lr] = f2bf(o[nt][r] * ri[r]);
        }
    }
}

// ---------------- host ----------------

extern "C" void kernel_launch(void* const* d_in, const int* in_sizes, int n_in,
                              void* d_out, int out_size, void* d_ws, size_t ws_size,
                              hipStream_t stream) {
    const float* x  = (const float*)d_in[0];
    const float* Wq = (const float*)d_in[1];
    const float* Wk = (const float*)d_in[2];
    const float* Wo = (const float*)d_in[3];
    float* out = (float*)d_out;
    char* ws = (char*)d_ws;

    unsigned short* xb  = (unsigned short*)(ws);
    unsigned short* wqt = (unsigned short*)(ws + 8388608);
    unsigned short* wkt = (unsigned short*)(ws + 9699328);
    unsigned short* wob = (unsigned short*)(ws + 11010048);
    char* dyn = ws + 12320768;

    cast_f32_bf16<<<4096, 256, 0, stream>>>(x, xb, BS_TOT * DIM);
    cast_f32_bf16<<<640, 256, 0, stream>>>(Wo, wob, DIM * HD);
    transpose_cast_w<<<dim3(8, 8, 2 * NH), 256, 0, stream>>>(Wq, Wk, wqt, wkt);

    const long perHeadElems = (long)BS_TOT * DIM;                // 4,194,304 (8MB bf16)
    const size_t FULL_NEED = 12320768ULL + 3ULL * 83886080ULL;   // ~264 MB (round-1 proven)

    if (ws_size >= FULL_NEED) {
        unsigned short* Qb  = (unsigned short*)dyn;              // also O (aliased)
        unsigned short* Kb  = Qb + (long)NH * perHeadElems;
        unsigned short* KTb = Kb + (long)NH * perHeadElems;
        proj_kernel<<<dim3(256, NH, 2), 256, 0, stream>>>(xb, wqt, wkt, Qb, Kb, KTb,
                                                          0, perHeadElems, perHeadElems);
        // O overwrites Q in-place (per-head-major), 2560 blocks XCD-chunked (2560/8=320)
        attn_kernel<<<2560, 256, 0, stream>>>(Qb, Kb, perHeadElems, KTb, perHeadElems,
                                              Qb, 256, perHeadElems, 320);
        final_full<<<256, 256, 0, stream>>>(Qb, perHeadElems, wob, out);
    } else {
        unsigned short* Qh  = (unsigned short*)dyn;              // also O (aliased)
        unsigned short* Kh  = Qh + perHeadElems;
        unsigned short* KTh = Kh + perHeadElems;
        hipMemsetAsync(d_out, 0, (size_t)out_size * 4, stream);
        for (int h = 0; h < NH; ++h) {
            proj_kernel<<<dim3(256, 1, 2), 256, 0, stream>>>(xb, wqt, wkt, Qh, Kh, KTh, h, 0, 0);
            attn_kernel<<<256, 256, 0, stream>>>(Qh, Kh, 0, KTh, 0, Qh, 256, 0, 32);
            final_kernel<<<256, 256, 0, stream>>>(Qh, 256, wob + h * 256, HD, out, 256, 1);
        }
    }
}